// Round 1
// 865.224 us; speedup vs baseline: 7.0434x; 7.0434x over previous
//
#include <hip/hip_runtime.h>
#include <hip/hip_bf16.h>

// Problem constants
#define B_  8
#define C_  256
#define H_  96
#define W_  96
#define G_  8
#define CPG 32          // C_/G_
#define KK  9           // 3x3 taps
#define O_  72          // G_*KK conv out channels
#define HW  9216        // H_*W_
#define NPX 73728       // B_*HW (BN population per channel)

// ---------------- K1: per-(b,c) spatial mean (SGE gap) ----------------
__global__ __launch_bounds__(256) void gap_kernel(const float* __restrict__ x,
                                                  float* __restrict__ gap) {
    int bc = blockIdx.x;                     // 0..2047
    const float4* p = (const float4*)(x + (size_t)bc * HW);
    float sum = 0.f;
    for (int idx = threadIdx.x; idx < HW / 4; idx += 256) {
        float4 v = p[idx];
        sum += v.x + v.y + v.z + v.w;
    }
    #pragma unroll
    for (int m = 32; m >= 1; m >>= 1) sum += __shfl_xor(sum, m, 64);
    __shared__ float red[4];
    int wid = threadIdx.x >> 6;
    if ((threadIdx.x & 63) == 0) red[wid] = sum;
    __syncthreads();
    if (threadIdx.x == 0)
        gap[bc] = (red[0] + red[1] + red[2] + red[3]) * (1.f / (float)HW);
}

// ---------------- K2: xn = sum_ch xg*gap, + per-(b,g) sum/sumsq ----------------
__global__ __launch_bounds__(256) void xn_kernel(const float* __restrict__ x,
                                                 const float* __restrict__ gap,
                                                 float* __restrict__ xng,
                                                 float* __restrict__ sge_stats) {
    int blk = blockIdx.x;                    // B_*G_*36 = 2304
    int bg = blk / 36, chunk = blk % 36;
    int b = bg >> 3, g = bg & 7;
    int p = chunk * 256 + threadIdx.x;
    const float* xbase = x + ((size_t)b * C_ + g * CPG) * HW + p;
    const float* gp = gap + b * C_ + g * CPG;
    float v = 0.f;
    #pragma unroll
    for (int ch = 0; ch < CPG; ch++) v += xbase[(size_t)ch * HW] * gp[ch];
    xng[(size_t)bg * HW + p] = v;
    float v1 = v, v2 = v * v;
    #pragma unroll
    for (int m = 32; m >= 1; m >>= 1) {
        v1 += __shfl_xor(v1, m, 64);
        v2 += __shfl_xor(v2, m, 64);
    }
    __shared__ float r1[4], r2[4];
    int wid = threadIdx.x >> 6;
    if ((threadIdx.x & 63) == 0) { r1[wid] = v1; r2[wid] = v2; }
    __syncthreads();
    if (threadIdx.x == 0) {
        atomicAdd(&sge_stats[bg * 2 + 0], r1[0] + r1[1] + r1[2] + r1[3]);
        atomicAdd(&sge_stats[bg * 2 + 1], r2[0] + r2[1] + r2[2] + r2[3]);
    }
}

// ---------------- K3: gate = sigmoid(normalized(xn)*w + b), in place ----------------
__global__ __launch_bounds__(256) void gate_kernel(float* __restrict__ xng,
                                                   const float* __restrict__ stats,
                                                   const float* __restrict__ sw,
                                                   const float* __restrict__ sb) {
    int idx = blockIdx.x * 256 + threadIdx.x;    // exactly 589824
    int bg = idx / HW;
    int g = bg & 7;
    float sum = stats[bg * 2], sumsq = stats[bg * 2 + 1];
    float mean = sum * (1.f / (float)HW);
    float var = (sumsq - sum * mean) * (1.f / (float)(HW - 1));
    var = fmaxf(var, 0.f);
    float sd = sqrtf(var) + 1e-5f;
    float tv = (xng[idx] - mean) / sd * sw[g] + sb[g];
    xng[idx] = 1.f / (1.f + expf(-tv));
}

// ---------------- K4: 3x3 conv (reflect pad) + BN batch-stat accumulation ----------------
// De-spilled version: cc loop NOT unrolled (full unroll blew VGPR budget ->
// acc/xv spilled to scratch -> 12.4 GB of HBM writes). Weight reads from LDS
// vectorized as float4 pairs (48B-aligned rows, taps padded 9->12).
#define CCH 8
__global__ __launch_bounds__(256, 2) void conv_kernel(const float* __restrict__ x,
                                                      const float* __restrict__ w,
                                                      float* __restrict__ s,
                                                      float* __restrict__ bn_stats) {
    int blk = blockIdx.x;                    // B_*H_ = 768
    int n = blk / H_, i = blk % H_;
    int t = threadIdx.x;
    int lane = t & 31;                       // j base (j = lane + 32*jj)
    int og = t >> 5;                         // 0..7 -> o = og*9 + oo
    __shared__ float xs[CCH][3][98];
    __shared__ float wsh[CCH][O_][12];       // taps padded 9->12 (16B align)
    float acc[9][3];
    #pragma unroll
    for (int a = 0; a < 9; a++)
        #pragma unroll
        for (int b2 = 0; b2 < 3; b2++) acc[a][b2] = 0.f;

    const float* xb = x + (size_t)n * C_ * HW;

    for (int c0 = 0; c0 < C_; c0 += CCH) {
        for (int idx = t; idx < CCH * 3 * 98; idx += 256) {
            int cc = idx / (3 * 98), rem = idx % (3 * 98);
            int r = rem / 98, col = rem % 98;
            int gcol = col - 1;
            if (gcol < 0) gcol = 1; else if (gcol > 95) gcol = 94;
            int ri = i + r - 1;                       // reflect row, no array
            if (ri < 0) ri = 1; else if (ri > 95) ri = 94;
            xs[cc][r][col] = xb[(size_t)(c0 + cc) * HW + ri * W_ + gcol];
        }
        for (int idx = t; idx < CCH * O_ * 9; idx += 256) {
            int cc = idx / (O_ * 9), rem = idx % (O_ * 9);
            int o = rem / 9, tap = rem % 9;
            wsh[cc][o][tap] = w[((size_t)o * C_ + c0 + cc) * 9 + tap];
        }
        __syncthreads();
        #pragma unroll 1
        for (int cc = 0; cc < CCH; cc++) {
            float xv[3][3][3];               // [jj][r][dx] -- all static indices
            #pragma unroll
            for (int jj = 0; jj < 3; jj++) {
                int j = lane + jj * 32;
                #pragma unroll
                for (int r = 0; r < 3; r++) {
                    xv[jj][r][0] = xs[cc][r][j];
                    xv[jj][r][1] = xs[cc][r][j + 1];
                    xv[jj][r][2] = xs[cc][r][j + 2];
                }
            }
            const float* wp = &wsh[cc][og * 9][0];
            #pragma unroll
            for (int oo = 0; oo < 9; oo++) {
                const float4 wA = *(const float4*)(wp + oo * 12);      // w0..w3
                const float4 wB = *(const float4*)(wp + oo * 12 + 4);  // w4..w7
                const float w8  = wp[oo * 12 + 8];
                #pragma unroll
                for (int jj = 0; jj < 3; jj++) {
                    acc[oo][jj] += xv[jj][0][0] * wA.x + xv[jj][0][1] * wA.y + xv[jj][0][2] * wA.z
                                 + xv[jj][1][0] * wA.w + xv[jj][1][1] * wB.x + xv[jj][1][2] * wB.y
                                 + xv[jj][2][0] * wB.z + xv[jj][2][1] * wB.w + xv[jj][2][2] * w8;
                }
            }
        }
        __syncthreads();
    }
    // write s (coalesced over lanes) + per-channel stats
    #pragma unroll
    for (int oo = 0; oo < 9; oo++) {
        int o = og * 9 + oo;
        float* sp = s + ((size_t)(n * O_ + o) * H_ + i) * W_;
        #pragma unroll
        for (int jj = 0; jj < 3; jj++) sp[lane + jj * 32] = acc[oo][jj];
        float v1 = acc[oo][0] + acc[oo][1] + acc[oo][2];
        float v2 = acc[oo][0] * acc[oo][0] + acc[oo][1] * acc[oo][1] + acc[oo][2] * acc[oo][2];
        #pragma unroll
        for (int m = 16; m >= 1; m >>= 1) {
            v1 += __shfl_xor(v1, m, 32);
            v2 += __shfl_xor(v2, m, 32);
        }
        if (lane == 0) {
            atomicAdd(&bn_stats[o * 2 + 0], v1);
            atomicAdd(&bn_stats[o * 2 + 1], v2);
        }
    }
}

// ---------------- K6: BN + softmax(72) + 9-tap gather * gate * sigma ----------------
__global__ __launch_bounds__(256, 2) void out_kernel(const float* __restrict__ x,
                                                     const float* __restrict__ s,
                                                     const float* __restrict__ bn_stats,
                                                     const float* __restrict__ gamma,
                                                     const float* __restrict__ beta,
                                                     const float* __restrict__ gate,
                                                     float* __restrict__ out) {
    int blk = blockIdx.x;                    // 768
    int n = blk / H_, i = blk % H_;
    int t = threadIdx.x;
    __shared__ float sg[O_][W_];             // exp(bn(s)) for this row
    __shared__ float rden[W_];
    __shared__ float gt[G_][3][98];          // gate at reflected tap coords

    int r0 = i - 1; if (r0 < 0) r0 = 1;
    int r2 = i + 1; if (r2 > 95) r2 = 94;
    int rows[3] = { r0, i, r2 };

    for (int idx = t; idx < G_ * 3 * 98; idx += 256) {
        int g = idx / (3 * 98), rem = idx % (3 * 98);
        int r = rem / 98, col = rem % 98;
        int gcol = col - 1;
        if (gcol < 0) gcol = 1; else if (gcol > 95) gcol = 94;
        gt[g][r][col] = gate[((size_t)(n * G_ + g)) * HW + rows[r] * W_ + gcol];
    }
    const float inv = 1.f / (float)NPX;
    for (int idx = t; idx < O_ * W_; idx += 256) {
        int o = idx / W_, j = idx % W_;
        float sum = bn_stats[o * 2], ssq = bn_stats[o * 2 + 1];
        float mean = sum * inv;
        float var = ssq * inv - mean * mean;
        float sc = rsqrtf(var + 1e-5f) * gamma[o];
        float val = (s[((size_t)(n * O_ + o) * H_ + i) * W_ + j] - mean) * sc + beta[o];
        sg[o][j] = expf(val);
    }
    __syncthreads();
    if (t < W_) {
        float d = 0.f;
        #pragma unroll
        for (int o = 0; o < O_; o++) d += sg[o][t];
        rden[t] = 1.f / d;
    }
    __syncthreads();

    const float* xb = x + (size_t)n * C_ * HW;
    for (int idx = t; idx < C_ * W_; idx += 256) {
        int c = idx / W_, j = idx % W_;
        int g = c >> 5;
        const float* xc = xb + (size_t)c * HW;
        int jm1 = j - 1; if (jm1 < 0) jm1 = 1;
        int jp1 = j + 1; if (jp1 > 95) jp1 = 94;
        int cols[3] = { jm1, j, jp1 };
        float acc = 0.f;
        #pragma unroll
        for (int r = 0; r < 3; r++) {
            const float* xr = xc + rows[r] * W_;
            #pragma unroll
            for (int dx = 0; dx < 3; dx++) {
                float xv = xr[cols[dx]];
                float gv = gt[g][r][j + dx];
                float sv = sg[g * 9 + r * 3 + dx][j];
                acc += xv * gv * sv;
            }
        }
        out[((size_t)(n * C_ + c) * H_ + i) * W_ + j] = acc * rden[j];
    }
}

extern "C" void kernel_launch(void* const* d_in, const int* in_sizes, int n_in,
                              void* d_out, int out_size, void* d_ws, size_t ws_size,
                              hipStream_t stream) {
    const float* x      = (const float*)d_in[0];
    const float* sge_w  = (const float*)d_in[1];
    const float* sge_b  = (const float*)d_in[2];
    const float* conv_w = (const float*)d_in[3];
    const float* gamma  = (const float*)d_in[4];
    const float* beta   = (const float*)d_in[5];
    float* out = (float*)d_out;
    float* ws = (float*)d_ws;

    // workspace layout (floats)
    float* sge_stats = ws;            // 128   (sum,sumsq per b*g)
    float* bn_stats  = ws + 128;      // 144   (sum,sumsq per o)
    float* gap       = ws + 272;      // 2048
    float* xng       = ws + 2320;     // 589824 (xn, overwritten in-place by gate)
    float* s         = ws + 592144;   // 5308416 conv output
    // total ~23.6 MB

    hipMemsetAsync(d_ws, 0, 272 * sizeof(float), stream);  // zero stats each call
    hipLaunchKernelGGL(gap_kernel,  dim3(B_ * C_),      dim3(256), 0, stream, x, gap);
    hipLaunchKernelGGL(xn_kernel,   dim3(B_ * G_ * 36), dim3(256), 0, stream, x, gap, xng, sge_stats);
    hipLaunchKernelGGL(gate_kernel, dim3(B_ * G_ * 36), dim3(256), 0, stream, xng, sge_stats, sge_w, sge_b);
    hipLaunchKernelGGL(conv_kernel, dim3(B_ * H_),      dim3(256), 0, stream, x, conv_w, s, bn_stats);
    hipLaunchKernelGGL(out_kernel,  dim3(B_ * H_),      dim3(256), 0, stream, x, s, bn_stats, gamma, beta, xng, out);
}

// Round 2
// 646.520 us; speedup vs baseline: 9.4261x; 1.3383x over previous
//
#include <hip/hip_runtime.h>
#include <hip/hip_bf16.h>

// Problem constants
#define B_  8
#define C_  256
#define H_  96
#define W_  96
#define G_  8
#define CPG 32          // C_/G_
#define KK  9           // 3x3 taps
#define O_  72          // G_*KK conv out channels
#define HW  9216        // H_*W_
#define NPX 73728       // B_*HW (BN population per channel)
#define WSTR 84         // wT per-(og,c) stride: 81 used, padded to 84 (336B, 16B-aligned)

// ---------------- K0: weight transpose  w[o][c][tap] -> wT[og][c][oo*9+tap] ----------------
__global__ __launch_bounds__(256) void wprep_kernel(const float* __restrict__ w,
                                                    float* __restrict__ wt) {
    int idx = blockIdx.x * 256 + threadIdx.x;        // O_*C_*KK = 165888
    if (idx >= O_ * C_ * KK) return;
    int tap = idx % 9;
    int rem = idx / 9;
    int c = rem % C_;
    int o = rem / C_;
    int og = o / 9, oo = o % 9;
    wt[((size_t)og * C_ + c) * WSTR + oo * 9 + tap] = w[idx];
}

// ---------------- K1: per-(b,c) spatial mean (SGE gap) ----------------
__global__ __launch_bounds__(256) void gap_kernel(const float* __restrict__ x,
                                                  float* __restrict__ gap) {
    int bc = blockIdx.x;                     // 0..2047
    const float4* p = (const float4*)(x + (size_t)bc * HW);
    float sum = 0.f;
    for (int idx = threadIdx.x; idx < HW / 4; idx += 256) {
        float4 v = p[idx];
        sum += v.x + v.y + v.z + v.w;
    }
    #pragma unroll
    for (int m = 32; m >= 1; m >>= 1) sum += __shfl_xor(sum, m, 64);
    __shared__ float red[4];
    int wid = threadIdx.x >> 6;
    if ((threadIdx.x & 63) == 0) red[wid] = sum;
    __syncthreads();
    if (threadIdx.x == 0)
        gap[bc] = (red[0] + red[1] + red[2] + red[3]) * (1.f / (float)HW);
}

// ---------------- K2: xn = sum_ch xg*gap, + per-(b,g) sum/sumsq ----------------
__global__ __launch_bounds__(256) void xn_kernel(const float* __restrict__ x,
                                                 const float* __restrict__ gap,
                                                 float* __restrict__ xng,
                                                 float* __restrict__ sge_stats) {
    int blk = blockIdx.x;                    // B_*G_*36 = 2304
    int bg = blk / 36, chunk = blk % 36;
    int b = bg >> 3, g = bg & 7;
    int p = chunk * 256 + threadIdx.x;
    const float* xbase = x + ((size_t)b * C_ + g * CPG) * HW + p;
    const float* gp = gap + b * C_ + g * CPG;
    float v = 0.f;
    #pragma unroll
    for (int ch = 0; ch < CPG; ch++) v += xbase[(size_t)ch * HW] * gp[ch];
    xng[(size_t)bg * HW + p] = v;
    float v1 = v, v2 = v * v;
    #pragma unroll
    for (int m = 32; m >= 1; m >>= 1) {
        v1 += __shfl_xor(v1, m, 64);
        v2 += __shfl_xor(v2, m, 64);
    }
    __shared__ float r1[4], r2[4];
    int wid = threadIdx.x >> 6;
    if ((threadIdx.x & 63) == 0) { r1[wid] = v1; r2[wid] = v2; }
    __syncthreads();
    if (threadIdx.x == 0) {
        atomicAdd(&sge_stats[bg * 2 + 0], r1[0] + r1[1] + r1[2] + r1[3]);
        atomicAdd(&sge_stats[bg * 2 + 1], r2[0] + r2[1] + r2[2] + r2[3]);
    }
}

// ---------------- K3: gate = sigmoid(normalized(xn)*w + b), in place ----------------
__global__ __launch_bounds__(256) void gate_kernel(float* __restrict__ xng,
                                                   const float* __restrict__ stats,
                                                   const float* __restrict__ sw,
                                                   const float* __restrict__ sb) {
    int idx = blockIdx.x * 256 + threadIdx.x;    // exactly 589824
    int bg = idx / HW;
    int g = bg & 7;
    float sum = stats[bg * 2], sumsq = stats[bg * 2 + 1];
    float mean = sum * (1.f / (float)HW);
    float var = (sumsq - sum * mean) * (1.f / (float)(HW - 1));
    var = fmaxf(var, 0.f);
    float sd = sqrtf(var) + 1e-5f;
    float tv = (xng[idx] - mean) / sd * sw[g] + sb[g];
    xng[idx] = 1.f / (1.f + expf(-tv));
}

// ---------------- K4: 3x3 conv (reflect pad) + BN batch-stat accumulation ----------------
// v3: LDS-pipe relief.
//  - weights in SGPRs: wave-uniform og (readfirstlane) + transposed wT layout ->
//    uniform loads compile to s_load; FMA uses the scalar operand. No weight LDS at all.
//  - 3 consecutive px per lane (2 rows/block): 15 ds_read_b32 per 243 FMAs (was 54 DS ops).
//    stride-3 lane addressing -> 2 lanes/bank (free).
//  - grid 768 = 48 row-pairs x 8 n x 2 og-halves; XCD-chunked so og-half mates share L2.
#define CCH 8
__global__ __launch_bounds__(256, 2) void conv_kernel(const float* __restrict__ x,
                                                      const float* __restrict__ wt,
                                                      float* __restrict__ s,
                                                      float* __restrict__ bn_stats) {
    int phys = blockIdx.x;                       // 768 blocks
    int blk = (phys & 7) * 96 + (phys >> 3);     // bijective XCD chunking (768 = 8*96)
    int ogsel = blk & 1;
    int np = blk >> 1;                           // 0..383
    int n = np / 48, pair = np % 48;
    int i0 = pair * 2;
    int t = threadIdx.x;
    int wid = t >> 6;                            // wave 0..3
    int lane = t & 63;
    int row = lane >> 5;                         // output row within pair: 0/1
    int k = lane & 31;                           // col group: output cols 3k..3k+2
    int og = __builtin_amdgcn_readfirstlane(ogsel * 4 + wid);   // wave-uniform

    __shared__ float xs[CCH][4][98];             // input rows i0-1..i0+2 (reflected)

    float acc[9][3];
    #pragma unroll
    for (int a = 0; a < 9; a++)
        #pragma unroll
        for (int b2 = 0; b2 < 3; b2++) acc[a][b2] = 0.f;

    const float* xb = x + (size_t)n * C_ * HW;

    for (int c0 = 0; c0 < C_; c0 += CCH) {
        for (int idx = t; idx < CCH * 4 * 98; idx += 256) {
            int cc = idx / (4 * 98), rem = idx % (4 * 98);
            int r = rem / 98, col = rem % 98;
            int gcol = col - 1;
            if (gcol < 0) gcol = 1; else if (gcol > 95) gcol = 94;
            int ri = i0 - 1 + r;                 // reflect rows, no runtime-indexed array
            if (ri < 0) ri = 1; else if (ri > 95) ri = 94;
            xs[cc][r][col] = xb[(size_t)(c0 + cc) * HW + ri * W_ + gcol];
        }
        __syncthreads();
        #pragma unroll 1
        for (int cc = 0; cc < CCH; cc++) {
            float xv[3][5];                      // [input row][col], static indices only
            #pragma unroll
            for (int r = 0; r < 3; r++)
                #pragma unroll
                for (int d = 0; d < 5; d++)
                    xv[r][d] = xs[cc][row + r][3 * k + d];
            const float* wp = wt + ((size_t)og * C_ + (c0 + cc)) * WSTR;  // uniform -> s_load
            #pragma unroll
            for (int oo = 0; oo < 9; oo++) {
                float w0 = wp[oo * 9 + 0], w1 = wp[oo * 9 + 1], w2 = wp[oo * 9 + 2];
                float w3 = wp[oo * 9 + 3], w4 = wp[oo * 9 + 4], w5 = wp[oo * 9 + 5];
                float w6 = wp[oo * 9 + 6], w7 = wp[oo * 9 + 7], w8 = wp[oo * 9 + 8];
                #pragma unroll
                for (int px = 0; px < 3; px++) {
                    acc[oo][px] += xv[0][px] * w0 + xv[0][px + 1] * w1 + xv[0][px + 2] * w2
                                 + xv[1][px] * w3 + xv[1][px + 1] * w4 + xv[1][px + 2] * w5
                                 + xv[2][px] * w6 + xv[2][px + 1] * w7 + xv[2][px + 2] * w8;
                }
            }
        }
        __syncthreads();
    }

    // write s (lane k writes cols 3k..3k+2, contiguous per wave) + per-channel stats
    int i = i0 + row;
    #pragma unroll
    for (int oo = 0; oo < 9; oo++) {
        int o = og * 9 + oo;
        float* sp = s + ((size_t)(n * O_ + o) * H_ + i) * W_ + 3 * k;
        sp[0] = acc[oo][0]; sp[1] = acc[oo][1]; sp[2] = acc[oo][2];
        float v1 = acc[oo][0] + acc[oo][1] + acc[oo][2];
        float v2 = acc[oo][0] * acc[oo][0] + acc[oo][1] * acc[oo][1] + acc[oo][2] * acc[oo][2];
        #pragma unroll
        for (int m = 32; m >= 1; m >>= 1) {
            v1 += __shfl_xor(v1, m, 64);
            v2 += __shfl_xor(v2, m, 64);
        }
        if (lane == 0) {
            atomicAdd(&bn_stats[o * 2 + 0], v1);
            atomicAdd(&bn_stats[o * 2 + 1], v2);
        }
    }
}

// ---------------- K6: BN + softmax(72) + 9-tap gather * gate * sigma ----------------
__global__ __launch_bounds__(256, 2) void out_kernel(const float* __restrict__ x,
                                                     const float* __restrict__ s,
                                                     const float* __restrict__ bn_stats,
                                                     const float* __restrict__ gamma,
                                                     const float* __restrict__ beta,
                                                     const float* __restrict__ gate,
                                                     float* __restrict__ out) {
    int blk = blockIdx.x;                    // 768
    int n = blk / H_, i = blk % H_;
    int t = threadIdx.x;
    __shared__ float sg[O_][W_];             // exp(bn(s)) for this row
    __shared__ float rden[W_];
    __shared__ float gt[G_][3][98];          // gate at reflected tap coords

    int r0 = i - 1; if (r0 < 0) r0 = 1;
    int r2 = i + 1; if (r2 > 95) r2 = 94;
    int rows[3] = { r0, i, r2 };

    for (int idx = t; idx < G_ * 3 * 98; idx += 256) {
        int g = idx / (3 * 98), rem = idx % (3 * 98);
        int r = rem / 98, col = rem % 98;
        int gcol = col - 1;
        if (gcol < 0) gcol = 1; else if (gcol > 95) gcol = 94;
        gt[g][r][col] = gate[((size_t)(n * G_ + g)) * HW + rows[r] * W_ + gcol];
    }
    const float inv = 1.f / (float)NPX;
    for (int idx = t; idx < O_ * W_; idx += 256) {
        int o = idx / W_, j = idx % W_;
        float sum = bn_stats[o * 2], ssq = bn_stats[o * 2 + 1];
        float mean = sum * inv;
        float var = ssq * inv - mean * mean;
        float sc = rsqrtf(var + 1e-5f) * gamma[o];
        float val = (s[((size_t)(n * O_ + o) * H_ + i) * W_ + j] - mean) * sc + beta[o];
        sg[o][j] = expf(val);
    }
    __syncthreads();
    if (t < W_) {
        float d = 0.f;
        #pragma unroll
        for (int o = 0; o < O_; o++) d += sg[o][t];
        rden[t] = 1.f / d;
    }
    __syncthreads();

    const float* xb = x + (size_t)n * C_ * HW;
    for (int idx = t; idx < C_ * W_; idx += 256) {
        int c = idx / W_, j = idx % W_;
        int g = c >> 5;
        const float* xc = xb + (size_t)c * HW;
        int jm1 = j - 1; if (jm1 < 0) jm1 = 1;
        int jp1 = j + 1; if (jp1 > 95) jp1 = 94;
        int cols[3] = { jm1, j, jp1 };
        float acc = 0.f;
        #pragma unroll
        for (int r = 0; r < 3; r++) {
            const float* xr = xc + rows[r] * W_;
            #pragma unroll
            for (int dx = 0; dx < 3; dx++) {
                float xv = xr[cols[dx]];
                float gv = gt[g][r][j + dx];
                float sv = sg[g * 9 + r * 3 + dx][j];
                acc += xv * gv * sv;
            }
        }
        out[((size_t)(n * C_ + c) * H_ + i) * W_ + j] = acc * rden[j];
    }
}

extern "C" void kernel_launch(void* const* d_in, const int* in_sizes, int n_in,
                              void* d_out, int out_size, void* d_ws, size_t ws_size,
                              hipStream_t stream) {
    const float* x      = (const float*)d_in[0];
    const float* sge_w  = (const float*)d_in[1];
    const float* sge_b  = (const float*)d_in[2];
    const float* conv_w = (const float*)d_in[3];
    const float* gamma  = (const float*)d_in[4];
    const float* beta   = (const float*)d_in[5];
    float* out = (float*)d_out;
    float* ws = (float*)d_ws;

    // workspace layout (floats)
    float* sge_stats = ws;            // 128    (sum,sumsq per b*g)
    float* bn_stats  = ws + 128;      // 144    (sum,sumsq per o)
    float* gap       = ws + 272;      // 2048
    float* xng       = ws + 2320;     // 589824 (xn, overwritten in-place by gate)
    float* s         = ws + 592144;   // 5308416 conv output
    float* wt        = ws + 5900560;  // 172032 transposed weights (8*256*84)
    // total ~24.3 MB

    hipMemsetAsync(d_ws, 0, 272 * sizeof(float), stream);  // zero stats each call
    hipLaunchKernelGGL(wprep_kernel, dim3(648),         dim3(256), 0, stream, conv_w, wt);
    hipLaunchKernelGGL(gap_kernel,   dim3(B_ * C_),     dim3(256), 0, stream, x, gap);
    hipLaunchKernelGGL(xn_kernel,    dim3(B_ * G_ * 36),dim3(256), 0, stream, x, gap, xng, sge_stats);
    hipLaunchKernelGGL(gate_kernel,  dim3(B_ * G_ * 36),dim3(256), 0, stream, xng, sge_stats, sge_w, sge_b);
    hipLaunchKernelGGL(conv_kernel,  dim3(768),         dim3(256), 0, stream, x, wt, s, bn_stats);
    hipLaunchKernelGGL(out_kernel,   dim3(B_ * H_),     dim3(256), 0, stream, x, s, bn_stats, gamma, beta, xng, out);
}

// Round 3
// 559.225 us; speedup vs baseline: 10.8975x; 1.1561x over previous
//
#include <hip/hip_runtime.h>
#include <hip/hip_bf16.h>

// Problem constants
#define B_  8
#define C_  256
#define H_  96
#define W_  96
#define G_  8
#define CPG 32          // C_/G_
#define KK  9           // 3x3 taps
#define O_  72          // G_*KK conv out channels
#define HW  9216        // H_*W_
#define NPX 73728       // B_*HW (BN population per channel)
#define WSTR 84         // wT per-(og,c) stride: 81 used, padded to 84 (336B, 16B-aligned)

// ---------------- K0: weight transpose  w[o][c][tap] -> wT[og][c][oo*9+tap] ----------------
__global__ __launch_bounds__(256) void wprep_kernel(const float* __restrict__ w,
                                                    float* __restrict__ wt) {
    int idx = blockIdx.x * 256 + threadIdx.x;        // O_*C_*KK = 165888
    if (idx >= O_ * C_ * KK) return;
    int tap = idx % 9;
    int rem = idx / 9;
    int c = rem % C_;
    int o = rem / C_;
    int og = o / 9, oo = o % 9;
    wt[((size_t)og * C_ + c) * WSTR + oo * 9 + tap] = w[idx];
}

// ---------------- K1: per-(b,c) spatial mean (SGE gap) ----------------
__global__ __launch_bounds__(256) void gap_kernel(const float* __restrict__ x,
                                                  float* __restrict__ gap) {
    int bc = blockIdx.x;                     // 0..2047
    const float4* p = (const float4*)(x + (size_t)bc * HW);
    float sum = 0.f;
    for (int idx = threadIdx.x; idx < HW / 4; idx += 256) {
        float4 v = p[idx];
        sum += v.x + v.y + v.z + v.w;
    }
    #pragma unroll
    for (int m = 32; m >= 1; m >>= 1) sum += __shfl_xor(sum, m, 64);
    __shared__ float red[4];
    int wid = threadIdx.x >> 6;
    if ((threadIdx.x & 63) == 0) red[wid] = sum;
    __syncthreads();
    if (threadIdx.x == 0)
        gap[bc] = (red[0] + red[1] + red[2] + red[3]) * (1.f / (float)HW);
}

// ---------------- K2: xn = sum_ch xg*gap, + per-(b,g) sum/sumsq ----------------
__global__ __launch_bounds__(256) void xn_kernel(const float* __restrict__ x,
                                                 const float* __restrict__ gap,
                                                 float* __restrict__ xng,
                                                 float* __restrict__ sge_stats) {
    int blk = blockIdx.x;                    // B_*G_*36 = 2304
    int bg = blk / 36, chunk = blk % 36;
    int b = bg >> 3, g = bg & 7;
    int p = chunk * 256 + threadIdx.x;
    const float* xbase = x + ((size_t)b * C_ + g * CPG) * HW + p;
    const float* gp = gap + b * C_ + g * CPG;
    float v = 0.f;
    #pragma unroll
    for (int ch = 0; ch < CPG; ch++) v += xbase[(size_t)ch * HW] * gp[ch];
    xng[(size_t)bg * HW + p] = v;
    float v1 = v, v2 = v * v;
    #pragma unroll
    for (int m = 32; m >= 1; m >>= 1) {
        v1 += __shfl_xor(v1, m, 64);
        v2 += __shfl_xor(v2, m, 64);
    }
    __shared__ float r1[4], r2[4];
    int wid = threadIdx.x >> 6;
    if ((threadIdx.x & 63) == 0) { r1[wid] = v1; r2[wid] = v2; }
    __syncthreads();
    if (threadIdx.x == 0) {
        atomicAdd(&sge_stats[bg * 2 + 0], r1[0] + r1[1] + r1[2] + r1[3]);
        atomicAdd(&sge_stats[bg * 2 + 1], r2[0] + r2[1] + r2[2] + r2[3]);
    }
}

// ---------------- K3: gate = sigmoid(normalized(xn)*w + b), in place ----------------
__global__ __launch_bounds__(256) void gate_kernel(float* __restrict__ xng,
                                                   const float* __restrict__ stats,
                                                   const float* __restrict__ sw,
                                                   const float* __restrict__ sb) {
    int idx = blockIdx.x * 256 + threadIdx.x;    // exactly 589824
    int bg = idx / HW;
    int g = bg & 7;
    float sum = stats[bg * 2], sumsq = stats[bg * 2 + 1];
    float mean = sum * (1.f / (float)HW);
    float var = (sumsq - sum * mean) * (1.f / (float)(HW - 1));
    var = fmaxf(var, 0.f);
    float sd = sqrtf(var) + 1e-5f;
    float tv = (xng[idx] - mean) / sd * sw[g] + sb[g];
    xng[idx] = 1.f / (1.f + expf(-tv));
}

// ---------------- K4: 3x3 conv (reflect pad) + BN batch-stat accumulation ----------------
// v4: async-stage split + hoisted addressing.
//  - per-thread staging source offsets precomputed ONCE (div/mod chains were ~490
//    VALU-cy per chunk, rivaling the 486 FMA-cy — now 1 pointer bump per chunk).
//  - double-buffered xs: issue next chunk's 13 global loads -> regs BEFORE compute,
//    ds_write after compute, one barrier per chunk (T14). L2 latency hides under FMAs.
//  - weights stay in SGPRs via wave-uniform og + transposed wT (s_load path, R2-proven).
#define CCH 8
#define XS_ELEMS (CCH * 4 * 98)   // 3136 floats = 12544 B per buffer
__global__ __launch_bounds__(256, 2) void conv_kernel(const float* __restrict__ x,
                                                      const float* __restrict__ wt,
                                                      float* __restrict__ s,
                                                      float* __restrict__ bn_stats) {
    int phys = blockIdx.x;                       // 768 blocks
    int blk = (phys & 7) * 96 + (phys >> 3);     // bijective XCD chunking (768 = 8*96)
    int ogsel = blk & 1;
    int np = blk >> 1;                           // 0..383
    int n = np / 48, pair = np % 48;
    int i0 = pair * 2;
    int t = threadIdx.x;
    int wid = t >> 6;                            // wave 0..3
    int lane = t & 63;
    int row = lane >> 5;                         // output row within pair: 0/1
    int k = lane & 31;                           // col group: output cols 3k..3k+2
    int og = __builtin_amdgcn_readfirstlane(ogsel * 4 + wid);   // wave-uniform

    __shared__ float xs0[XS_ELEMS];
    __shared__ float xs1[XS_ELEMS];

    // ---- precompute per-thread staging source offsets (rel. to xb + c0*HW) ----
    int off[13];
    #pragma unroll
    for (int it = 0; it < 13; it++) {
        if (it == 12 && t >= 64) { off[it] = 0; continue; }
        int gidx = it * 256 + t;                 // 0..3135
        int cc = gidx / 392;
        int rem = gidx - cc * 392;
        int r = rem / 98;
        int col = rem - r * 98;
        int gcol = col - 1;
        if (gcol < 0) gcol = 1; else if (gcol > 95) gcol = 94;
        int ri = i0 - 1 + r;                     // reflected input row
        if (ri < 0) ri = 1; else if (ri > 95) ri = 94;
        off[it] = cc * HW + ri * W_ + gcol;
    }

    float acc[9][3];
    #pragma unroll
    for (int a = 0; a < 9; a++)
        #pragma unroll
        for (int b2 = 0; b2 < 3; b2++) acc[a][b2] = 0.f;

    const float* xb = x + (size_t)n * C_ * HW;
    float* bufA = xs0;                           // buffer being computed
    float* bufB = xs1;                           // buffer being filled

    // ---- prologue: stage chunk 0 into xs0 ----
    {
        float ld[13];
        #pragma unroll
        for (int it = 0; it < 12; it++) ld[it] = xb[off[it]];
        if (t < 64) ld[12] = xb[off[12]];
        #pragma unroll
        for (int it = 0; it < 12; it++) xs0[it * 256 + t] = ld[it];
        if (t < 64) xs0[12 * 256 + t] = ld[12];
    }
    __syncthreads();

    for (int c0 = 0; c0 < C_; c0 += CCH) {
        // phase A: issue next chunk's global loads (latency hides under compute)
        float ld[13];
        const bool have_next = (c0 + CCH < C_);
        if (have_next) {
            const float* src = xb + (size_t)(c0 + CCH) * HW;
            #pragma unroll
            for (int it = 0; it < 12; it++) ld[it] = src[off[it]];
            if (t < 64) ld[12] = src[off[12]];
        }
        // phase B: compute 8 channels from bufA
        #pragma unroll 1
        for (int cc = 0; cc < CCH; cc++) {
            float xv[3][5];                      // [input row][col], static indices only
            const float* xr = bufA + cc * 392;
            #pragma unroll
            for (int r = 0; r < 3; r++)
                #pragma unroll
                for (int d = 0; d < 5; d++)
                    xv[r][d] = xr[(row + r) * 98 + 3 * k + d];
            const float* wp = wt + ((size_t)og * C_ + (c0 + cc)) * WSTR;  // uniform -> s_load
            #pragma unroll
            for (int oo = 0; oo < 9; oo++) {
                float w0 = wp[oo * 9 + 0], w1 = wp[oo * 9 + 1], w2 = wp[oo * 9 + 2];
                float w3 = wp[oo * 9 + 3], w4 = wp[oo * 9 + 4], w5 = wp[oo * 9 + 5];
                float w6 = wp[oo * 9 + 6], w7 = wp[oo * 9 + 7], w8 = wp[oo * 9 + 8];
                #pragma unroll
                for (int px = 0; px < 3; px++) {
                    acc[oo][px] += xv[0][px] * w0 + xv[0][px + 1] * w1 + xv[0][px + 2] * w2
                                 + xv[1][px] * w3 + xv[1][px + 1] * w4 + xv[1][px + 2] * w5
                                 + xv[2][px] * w6 + xv[2][px + 1] * w7 + xv[2][px + 2] * w8;
                }
            }
        }
        // phase C: write staged regs into bufB, one barrier per chunk
        if (have_next) {
            #pragma unroll
            for (int it = 0; it < 12; it++) bufB[it * 256 + t] = ld[it];
            if (t < 64) bufB[12 * 256 + t] = ld[12];
        }
        __syncthreads();
        float* tmp = bufA; bufA = bufB; bufB = tmp;
    }

    // write s (lane k writes cols 3k..3k+2, contiguous per wave) + per-channel stats
    int i = i0 + row;
    #pragma unroll
    for (int oo = 0; oo < 9; oo++) {
        int o = og * 9 + oo;
        float* sp = s + ((size_t)(n * O_ + o) * H_ + i) * W_ + 3 * k;
        sp[0] = acc[oo][0]; sp[1] = acc[oo][1]; sp[2] = acc[oo][2];
        float v1 = acc[oo][0] + acc[oo][1] + acc[oo][2];
        float v2 = acc[oo][0] * acc[oo][0] + acc[oo][1] * acc[oo][1] + acc[oo][2] * acc[oo][2];
        #pragma unroll
        for (int m = 32; m >= 1; m >>= 1) {
            v1 += __shfl_xor(v1, m, 64);
            v2 += __shfl_xor(v2, m, 64);
        }
        if (lane == 0) {
            atomicAdd(&bn_stats[o * 2 + 0], v1);
            atomicAdd(&bn_stats[o * 2 + 1], v2);
        }
    }
}

// ---------------- K6: BN + softmax(72) + 9-tap gather * gate * sigma ----------------
__global__ __launch_bounds__(256, 2) void out_kernel(const float* __restrict__ x,
                                                     const float* __restrict__ s,
                                                     const float* __restrict__ bn_stats,
                                                     const float* __restrict__ gamma,
                                                     const float* __restrict__ beta,
                                                     const float* __restrict__ gate,
                                                     float* __restrict__ out) {
    int blk = blockIdx.x;                    // 768
    int n = blk / H_, i = blk % H_;
    int t = threadIdx.x;
    __shared__ float sg[O_][W_];             // exp(bn(s)) for this row
    __shared__ float rden[W_];
    __shared__ float gt[G_][3][98];          // gate at reflected tap coords

    int r0 = i - 1; if (r0 < 0) r0 = 1;
    int r2 = i + 1; if (r2 > 95) r2 = 94;
    int rows[3] = { r0, i, r2 };

    for (int idx = t; idx < G_ * 3 * 98; idx += 256) {
        int g = idx / (3 * 98), rem = idx % (3 * 98);
        int r = rem / 98, col = rem % 98;
        int gcol = col - 1;
        if (gcol < 0) gcol = 1; else if (gcol > 95) gcol = 94;
        gt[g][r][col] = gate[((size_t)(n * G_ + g)) * HW + rows[r] * W_ + gcol];
    }
    const float inv = 1.f / (float)NPX;
    for (int idx = t; idx < O_ * W_; idx += 256) {
        int o = idx / W_, j = idx % W_;
        float sum = bn_stats[o * 2], ssq = bn_stats[o * 2 + 1];
        float mean = sum * inv;
        float var = ssq * inv - mean * mean;
        float sc = rsqrtf(var + 1e-5f) * gamma[o];
        float val = (s[((size_t)(n * O_ + o) * H_ + i) * W_ + j] - mean) * sc + beta[o];
        sg[o][j] = expf(val);
    }
    __syncthreads();
    if (t < W_) {
        float d = 0.f;
        #pragma unroll
        for (int o = 0; o < O_; o++) d += sg[o][t];
        rden[t] = 1.f / d;
    }
    __syncthreads();

    const float* xb = x + (size_t)n * C_ * HW;
    for (int idx = t; idx < C_ * W_; idx += 256) {
        int c = idx / W_, j = idx % W_;
        int g = c >> 5;
        const float* xc = xb + (size_t)c * HW;
        int jm1 = j - 1; if (jm1 < 0) jm1 = 1;
        int jp1 = j + 1; if (jp1 > 95) jp1 = 94;
        int cols[3] = { jm1, j, jp1 };
        float acc = 0.f;
        #pragma unroll
        for (int r = 0; r < 3; r++) {
            const float* xr = xc + rows[r] * W_;
            #pragma unroll
            for (int dx = 0; dx < 3; dx++) {
                float xv = xr[cols[dx]];
                float gv = gt[g][r][j + dx];
                float sv = sg[g * 9 + r * 3 + dx][j];
                acc += xv * gv * sv;
            }
        }
        out[((size_t)(n * C_ + c) * H_ + i) * W_ + j] = acc * rden[j];
    }
}

extern "C" void kernel_launch(void* const* d_in, const int* in_sizes, int n_in,
                              void* d_out, int out_size, void* d_ws, size_t ws_size,
                              hipStream_t stream) {
    const float* x      = (const float*)d_in[0];
    const float* sge_w  = (const float*)d_in[1];
    const float* sge_b  = (const float*)d_in[2];
    const float* conv_w = (const float*)d_in[3];
    const float* gamma  = (const float*)d_in[4];
    const float* beta   = (const float*)d_in[5];
    float* out = (float*)d_out;
    float* ws = (float*)d_ws;

    // workspace layout (floats)
    float* sge_stats = ws;            // 128    (sum,sumsq per b*g)
    float* bn_stats  = ws + 128;      // 144    (sum,sumsq per o)
    float* gap       = ws + 272;      // 2048
    float* xng       = ws + 2320;     // 589824 (xn, overwritten in-place by gate)
    float* s         = ws + 592144;   // 5308416 conv output
    float* wt        = ws + 5900560;  // 172032 transposed weights (8*256*84)
    // total ~24.3 MB

    hipMemsetAsync(d_ws, 0, 272 * sizeof(float), stream);  // zero stats each call
    hipLaunchKernelGGL(wprep_kernel, dim3(648),         dim3(256), 0, stream, conv_w, wt);
    hipLaunchKernelGGL(gap_kernel,   dim3(B_ * C_),     dim3(256), 0, stream, x, gap);
    hipLaunchKernelGGL(xn_kernel,    dim3(B_ * G_ * 36),dim3(256), 0, stream, x, gap, xng, sge_stats);
    hipLaunchKernelGGL(gate_kernel,  dim3(B_ * G_ * 36),dim3(256), 0, stream, xng, sge_stats, sge_w, sge_b);
    hipLaunchKernelGGL(conv_kernel,  dim3(768),         dim3(256), 0, stream, x, wt, s, bn_stats);
    hipLaunchKernelGGL(out_kernel,   dim3(B_ * H_),     dim3(256), 0, stream, x, s, bn_stats, gamma, beta, xng, out);
}